// Round 1
// baseline (327.493 us; speedup 1.0000x reference)
//
#include <hip/hip_runtime.h>
#include <hip/hip_bf16.h>

// Fused WindowAttention: x @ W_qkv + b -> MHA(16 heads, D=64) -> @ W_proj + b
// B=8, N=1024, C=1024. All fp32 in/out; internal compute bf16 MFMA + fp32 accum.
//
// Workspace layout (bf16 = ushort), needs 64 MiB:
//   Qb [B*H][N][64]   : 8388608 elems
//   Kb [B*H][N][64]   : 8388608
//   Vb [B*H][N][64]   : 8388608
//   Ab [B*N][C]       : 8388608  (attention output, pre-projection)

using bf16x8 = __attribute__((ext_vector_type(8))) short;
using f32x4  = __attribute__((ext_vector_type(4))) float;
using u16    = unsigned short;
using u16x4  = __attribute__((ext_vector_type(4))) unsigned short;
using u16x8  = __attribute__((ext_vector_type(8))) unsigned short;

__device__ __forceinline__ u16 f2bf(float f) {
  unsigned int u = __float_as_uint(f);
  u += 0x7FFFu + ((u >> 16) & 1u);   // RNE (finite inputs only)
  return (u16)(u >> 16);
}
__device__ __forceinline__ float bf2f(u16 h) {
  return __uint_as_float(((unsigned int)h) << 16);
}

// ---------------------------------------------------------------------------
// Kernel 1: QKV GEMM.  X[8192][1024] fp32 @ W[1024][3072] fp32 + bias
// -> Q/K/V bf16 in [B*H][N][64] layout.
// 128x128 tile, BK=32, 4 waves (2x2), each wave 64x64 = 4x4 16x16 frags.
// ---------------------------------------------------------------------------
__global__ __launch_bounds__(256, 2) void qkv_gemm(
    const float* __restrict__ X, const float* __restrict__ W,
    const float* __restrict__ bias,
    u16* __restrict__ Qb, u16* __restrict__ Kb, u16* __restrict__ Vb)
{
  constexpr int N = 3072, KD = 1024;
  __shared__ u16 As[128][48];   // [row][k], pad 32->48 (96B stride, 16B aligned)
  __shared__ u16 Bs[128][48];   // [col][k] (transposed W tile)

  const int tid = threadIdx.x;
  const int lane = tid & 63, wid = tid >> 6;
  const int wr = wid >> 1, wc = wid & 1;
  const int lg = lane >> 4, lc = lane & 15;
  const int row0 = blockIdx.x * 128;
  const int col0 = blockIdx.y * 128;

  f32x4 acc[4][4];
  #pragma unroll
  for (int m = 0; m < 4; ++m)
    #pragma unroll
    for (int n = 0; n < 4; ++n) acc[m][n] = (f32x4){0.f, 0.f, 0.f, 0.f};

  const int ar = tid >> 1, ac4 = (tid & 1) * 4;          // A: row, float4-seg
  const int bcs = (tid >> 4) * 8, bkp = (tid & 15) * 2;  // B: col-seg, k-pair

  for (int k0 = 0; k0 < KD; k0 += 32) {
    // stage A (fp32 -> bf16), coalesced 64B/thread
    const float* asrc = X + (size_t)(row0 + ar) * KD + k0 + ac4 * 4;
    #pragma unroll
    for (int i = 0; i < 4; ++i) {
      f32x4 v = *(const f32x4*)(asrc + i * 4);
      u16x4 h = { f2bf(v.x), f2bf(v.y), f2bf(v.z), f2bf(v.w) };
      *(u16x4*)&As[ar][(ac4 + i) * 4] = h;
    }
    // stage B transposed: 2 k-rows x 8 cols per thread, pack k-pairs into u32
    const float* b0 = W + (size_t)(k0 + bkp) * N + col0 + bcs;
    const float* b1 = b0 + N;
    f32x4 r0a = *(const f32x4*)b0, r0b = *(const f32x4*)(b0 + 4);
    f32x4 r1a = *(const f32x4*)b1, r1b = *(const f32x4*)(b1 + 4);
    #pragma unroll
    for (int c = 0; c < 4; ++c) {
      unsigned int p0 = (unsigned)f2bf(r0a[c]) | ((unsigned)f2bf(r1a[c]) << 16);
      unsigned int p1 = (unsigned)f2bf(r0b[c]) | ((unsigned)f2bf(r1b[c]) << 16);
      *(unsigned int*)&Bs[bcs + c][bkp]     = p0;
      *(unsigned int*)&Bs[bcs + 4 + c][bkp] = p1;
    }
    __syncthreads();

    bf16x8 a[4], b[4];
    #pragma unroll
    for (int m = 0; m < 4; ++m)
      a[m] = *(const bf16x8*)&As[wr * 64 + m * 16 + lc][lg * 8];
    #pragma unroll
    for (int n = 0; n < 4; ++n)
      b[n] = *(const bf16x8*)&Bs[wc * 64 + n * 16 + lc][lg * 8];
    #pragma unroll
    for (int m = 0; m < 4; ++m)
      #pragma unroll
      for (int n = 0; n < 4; ++n)
        acc[m][n] = __builtin_amdgcn_mfma_f32_16x16x32_bf16(a[m], b[n], acc[m][n], 0, 0, 0);
    __syncthreads();
  }

  // epilogue: +bias, scatter to Q/K/V [B*H][N][64] bf16
  #pragma unroll
  for (int m = 0; m < 4; ++m) {
    #pragma unroll
    for (int n = 0; n < 4; ++n) {
      #pragma unroll
      for (int r = 0; r < 4; ++r) {
        int gr = row0 + wr * 64 + m * 16 + lg * 4 + r;   // [0,8192)
        int gc = col0 + wc * 64 + n * 16 + lc;           // [0,3072)
        float val = acc[m][n][r] + bias[gc];
        int which = gc >> 10, ci = gc & 1023;
        int h = ci >> 6, d = ci & 63;
        int bb = gr >> 10, nn = gr & 1023;
        u16* dst = (which == 0) ? Qb : (which == 1) ? Kb : Vb;
        dst[((size_t)(bb * 16 + h) * 1024 + nn) * 64 + d] = f2bf(val);
      }
    }
  }
}

// ---------------------------------------------------------------------------
// Kernel 2: flash attention. One block = one (b,h) x 64 q-rows; 4 waves x 16.
// K-tiles of 64 keys, online softmax. S = Q@K^T (frag rows = q-rows),
// P staged per-wave in LDS to become the PV A-operand; V staged transposed.
// ---------------------------------------------------------------------------
__global__ __launch_bounds__(256, 2) void attn_kernel(
    const u16* __restrict__ Q, const u16* __restrict__ K,
    const u16* __restrict__ V, u16* __restrict__ O)
{
  __shared__ u16 Ks[64][72];       // [key][d]
  __shared__ u16 Vt[64][72];       // [d][key]
  __shared__ u16 Pl[4][16][72];    // per-wave P [qrow][key]

  const int tid = threadIdx.x, lane = tid & 63, wid = tid >> 6;
  const int lg = lane >> 4, lc = lane & 15;
  const int qt = blockIdx.x;       // q tile [0,16)
  const int bh = blockIdx.y;       // b*16+h [0,128)
  const size_t base = (size_t)bh * 1024 * 64;
  const u16* Qp = Q + base;
  const u16* Kp = K + base;
  const u16* Vp = V + base;

  // Q fragments, pre-scaled by 1/sqrt(64) = 0.125
  bf16x8 qf[2];
  {
    const u16* qsrc = Qp + (size_t)(qt * 64 + wid * 16 + lc) * 64 + lg * 8;
    #pragma unroll
    for (int ks = 0; ks < 2; ++ks) {
      u16x8 raw = *(const u16x8*)(qsrc + ks * 32);
      bf16x8 t;
      #pragma unroll
      for (int j = 0; j < 8; ++j) t[j] = (short)f2bf(bf2f(raw[j]) * 0.125f);
      qf[ks] = t;
    }
  }

  f32x4 o[4];
  #pragma unroll
  for (int fd = 0; fd < 4; ++fd) o[fd] = (f32x4){0.f, 0.f, 0.f, 0.f};
  float m_r[4] = {-1e30f, -1e30f, -1e30f, -1e30f};
  float l_r[4] = {0.f, 0.f, 0.f, 0.f};

  const int skr = tid >> 2, sds = (tid & 3) * 16;   // staging: key-row, d-seg

  for (int kt = 0; kt < 16; ++kt) {
    // stage K tile (as-is) and V tile (transposed)
    const u16* ksrc = Kp + (size_t)(kt * 64 + skr) * 64 + sds;
    u16x8 ka = *(const u16x8*)ksrc, kb2 = *(const u16x8*)(ksrc + 8);
    *(u16x8*)&Ks[skr][sds]     = ka;
    *(u16x8*)&Ks[skr][sds + 8] = kb2;
    const u16* vsrc = Vp + (size_t)(kt * 64 + skr) * 64 + sds;
    u16x8 va = *(const u16x8*)vsrc, vb = *(const u16x8*)(vsrc + 8);
    #pragma unroll
    for (int j = 0; j < 8; ++j) {
      Vt[sds + j][skr]     = va[j];
      Vt[sds + 8 + j][skr] = vb[j];
    }
    __syncthreads();

    // S = (Q*scale) @ K^T  : s[kb] covers keys kb*16..+16
    f32x4 s[4];
    #pragma unroll
    for (int kb = 0; kb < 4; ++kb) {
      s[kb] = (f32x4){0.f, 0.f, 0.f, 0.f};
      #pragma unroll
      for (int ks = 0; ks < 2; ++ks) {
        bf16x8 kf = *(const bf16x8*)&Ks[kb * 16 + lc][ks * 32 + lg * 8];
        s[kb] = __builtin_amdgcn_mfma_f32_16x16x32_bf16(qf[ks], kf, s[kb], 0, 0, 0);
      }
    }

    // online softmax (frag reg r = q-row lg*4+r; cols live in 16-lane group)
    #pragma unroll
    for (int r = 0; r < 4; ++r) {
      float t = fmaxf(fmaxf(s[0][r], s[1][r]), fmaxf(s[2][r], s[3][r]));
      #pragma unroll
      for (int off = 8; off >= 1; off >>= 1) t = fmaxf(t, __shfl_xor(t, off));
      float nm = fmaxf(m_r[r], t);
      float sc = __expf(m_r[r] - nm);
      m_r[r] = nm;
      l_r[r] *= sc;
      #pragma unroll
      for (int fd = 0; fd < 4; ++fd) o[fd][r] *= sc;
    }
    #pragma unroll
    for (int kb = 0; kb < 4; ++kb) {
      #pragma unroll
      for (int r = 0; r < 4; ++r) {
        float p = __expf(s[kb][r] - m_r[r]);
        l_r[r] += p;
        Pl[wid][lg * 4 + r][lc + kb * 16] = f2bf(p);
      }
    }

    // PV: O += P @ V   (P A-frags re-read from per-wave LDS; in-wave ordering)
    bf16x8 pa[2];
    #pragma unroll
    for (int ks = 0; ks < 2; ++ks)
      pa[ks] = *(const bf16x8*)&Pl[wid][lc][ks * 32 + lg * 8];
    #pragma unroll
    for (int fd = 0; fd < 4; ++fd) {
      #pragma unroll
      for (int ks = 0; ks < 2; ++ks) {
        bf16x8 vf = *(const bf16x8*)&Vt[fd * 16 + lc][ks * 32 + lg * 8];
        o[fd] = __builtin_amdgcn_mfma_f32_16x16x32_bf16(pa[ks], vf, o[fd], 0, 0, 0);
      }
    }
    __syncthreads();
  }

  // finalize: cross-lane sum of l, divide, store [B][N][C] bf16
  #pragma unroll
  for (int r = 0; r < 4; ++r) {
    float t = l_r[r];
    #pragma unroll
    for (int off = 8; off >= 1; off >>= 1) t += __shfl_xor(t, off);
    l_r[r] = 1.0f / t;
  }
  const int b = bh >> 4, h = bh & 15;
  #pragma unroll
  for (int fd = 0; fd < 4; ++fd) {
    #pragma unroll
    for (int r = 0; r < 4; ++r) {
      int n = qt * 64 + wid * 16 + lg * 4 + r;
      O[((size_t)b * 1024 + n) * 1024 + h * 64 + fd * 16 + lc] =
          f2bf(o[fd][r] * l_r[r]);
    }
  }
}

// ---------------------------------------------------------------------------
// Kernel 3: projection GEMM. A[8192][1024] bf16 @ W[1024][1024] fp32 + bias
// -> fp32 out. Same structure as kernel 1 (A already bf16).
// ---------------------------------------------------------------------------
__global__ __launch_bounds__(256, 2) void proj_gemm(
    const u16* __restrict__ A, const float* __restrict__ W,
    const float* __restrict__ bias, float* __restrict__ Out)
{
  constexpr int N = 1024, KD = 1024;
  __shared__ u16 As[128][48];
  __shared__ u16 Bs[128][48];

  const int tid = threadIdx.x;
  const int lane = tid & 63, wid = tid >> 6;
  const int wr = wid >> 1, wc = wid & 1;
  const int lg = lane >> 4, lc = lane & 15;
  const int row0 = blockIdx.x * 128;
  const int col0 = blockIdx.y * 128;

  f32x4 acc[4][4];
  #pragma unroll
  for (int m = 0; m < 4; ++m)
    #pragma unroll
    for (int n = 0; n < 4; ++n) acc[m][n] = (f32x4){0.f, 0.f, 0.f, 0.f};

  const int ar = tid >> 1, aseg = (tid & 1) * 16;
  const int bcs = (tid >> 4) * 8, bkp = (tid & 15) * 2;

  for (int k0 = 0; k0 < KD; k0 += 32) {
    const u16* asrc = A + (size_t)(row0 + ar) * KD + k0 + aseg;
    *(u16x8*)&As[ar][aseg]     = *(const u16x8*)asrc;
    *(u16x8*)&As[ar][aseg + 8] = *(const u16x8*)(asrc + 8);

    const float* b0 = W + (size_t)(k0 + bkp) * N + col0 + bcs;
    const float* b1 = b0 + N;
    f32x4 r0a = *(const f32x4*)b0, r0b = *(const f32x4*)(b0 + 4);
    f32x4 r1a = *(const f32x4*)b1, r1b = *(const f32x4*)(b1 + 4);
    #pragma unroll
    for (int c = 0; c < 4; ++c) {
      unsigned int p0 = (unsigned)f2bf(r0a[c]) | ((unsigned)f2bf(r1a[c]) << 16);
      unsigned int p1 = (unsigned)f2bf(r0b[c]) | ((unsigned)f2bf(r1b[c]) << 16);
      *(unsigned int*)&Bs[bcs + c][bkp]     = p0;
      *(unsigned int*)&Bs[bcs + 4 + c][bkp] = p1;
    }
    __syncthreads();

    bf16x8 a[4], b[4];
    #pragma unroll
    for (int m = 0; m < 4; ++m)
      a[m] = *(const bf16x8*)&As[wr * 64 + m * 16 + lc][lg * 8];
    #pragma unroll
    for (int n = 0; n < 4; ++n)
      b[n] = *(const bf16x8*)&Bs[wc * 64 + n * 16 + lc][lg * 8];
    #pragma unroll
    for (int m = 0; m < 4; ++m)
      #pragma unroll
      for (int n = 0; n < 4; ++n)
        acc[m][n] = __builtin_amdgcn_mfma_f32_16x16x32_bf16(a[m], b[n], acc[m][n], 0, 0, 0);
    __syncthreads();
  }

  #pragma unroll
  for (int m = 0; m < 4; ++m) {
    #pragma unroll
    for (int n = 0; n < 4; ++n) {
      #pragma unroll
      for (int r = 0; r < 4; ++r) {
        int gr = row0 + wr * 64 + m * 16 + lg * 4 + r;
        int gc = col0 + wc * 64 + n * 16 + lc;
        Out[(size_t)gr * N + gc] = acc[m][n][r] + bias[gc];
      }
    }
  }
}

// ---------------------------------------------------------------------------
extern "C" void kernel_launch(void* const* d_in, const int* in_sizes, int n_in,
                              void* d_out, int out_size, void* d_ws, size_t ws_size,
                              hipStream_t stream) {
  const float* x     = (const float*)d_in[0];
  const float* W_qkv = (const float*)d_in[1];
  const float* b_qkv = (const float*)d_in[2];
  const float* W_prj = (const float*)d_in[3];
  const float* b_prj = (const float*)d_in[4];
  float* out = (float*)d_out;

  u16* ws = (u16*)d_ws;                 // needs 64 MiB
  const size_t SEG = (size_t)8 * 16 * 1024 * 64;   // 8388608
  u16* Qb = ws;
  u16* Kb = Qb + SEG;
  u16* Vb = Kb + SEG;
  u16* Ab = Vb + SEG;

  qkv_gemm<<<dim3(64, 24), 256, 0, stream>>>(x, W_qkv, b_qkv, Qb, Kb, Vb);
  attn_kernel<<<dim3(16, 128), 256, 0, stream>>>(Qb, Kb, Vb, Ab);
  proj_gemm<<<dim3(64, 8), 256, 0, stream>>>(Ab, W_prj, b_prj, out);
}

// Round 2
// 221.526 us; speedup vs baseline: 1.4783x; 1.4783x over previous
//
#include <hip/hip_runtime.h>
#include <hip/hip_bf16.h>

// Fused WindowAttention: x @ W_qkv + b -> MHA(16 heads, D=64) -> @ W_proj + b
// B=8, N=1024, C=1024. fp32 in/out; internal bf16 MFMA + fp32 accum.
//
// Pipeline:
//   1. convert_f32_bf16 : X fp32 -> Xb bf16
//   2. transpose_w x2   : W_qkv -> Wqt [3072][1024] bf16, W_proj -> Wpt [1024][1024] bf16
//   3. qkv_gemm2 (m97-style, global_load_lds) -> Q/K/V bf16 [B*H][N][64]
//   4. attn_kernel (unchanged)               -> Ab bf16 [B*N][C]
//   5. proj_gemm2 (m97-style)                -> fp32 d_out
//
// Scratch: ws: [Xb|Ab 16.78M][Vb 16.78M][Wqt 6.29M][Wpt 2.10M] = 42 MB
//          d_out used as scratch for Qb(16.78M)+Kb(16.78M), overwritten by proj.

using bf16x8 = __attribute__((ext_vector_type(8))) short;
using f32x4  = __attribute__((ext_vector_type(4))) float;
using u16    = unsigned short;
using u16x8  = __attribute__((ext_vector_type(8))) unsigned short;

__device__ __forceinline__ u16 f2bf(float f) {
  unsigned int u = __float_as_uint(f);
  u += 0x7FFFu + ((u >> 16) & 1u);   // RNE (finite inputs only)
  return (u16)(u >> 16);
}
__device__ __forceinline__ float bf2f(u16 h) {
  return __uint_as_float(((unsigned int)h) << 16);
}

// async global->LDS, 16B per lane, writes lbase + lane*16 (wave-uniform base)
__device__ __forceinline__ void gload16(const u16* g, u16* lbase, int lane) {
#if __has_builtin(__builtin_amdgcn_global_load_lds)
  __builtin_amdgcn_global_load_lds(
      (const __attribute__((address_space(1))) void*)g,
      (__attribute__((address_space(3))) void*)lbase, 16, 0, 0);
#else
  *(u16x8*)(lbase + (size_t)lane * 8) = *(const u16x8*)g;
#endif
}

// ---------------------------------------------------------------------------
// Pre-pass 1: fp32 -> bf16, 8 elems/thread, exact-size grid
// ---------------------------------------------------------------------------
__global__ __launch_bounds__(256) void convert_f32_bf16(
    const float* __restrict__ in, u16* __restrict__ out)
{
  size_t i = ((size_t)blockIdx.x * 256 + threadIdx.x) * 8;
  f32x4 a = *(const f32x4*)(in + i);
  f32x4 b = *(const f32x4*)(in + i + 4);
  u16x8 h = { f2bf(a.x), f2bf(a.y), f2bf(a.z), f2bf(a.w),
              f2bf(b.x), f2bf(b.y), f2bf(b.z), f2bf(b.w) };
  *(u16x8*)(out + i) = h;
}

// ---------------------------------------------------------------------------
// Pre-pass 2: W [K][N] fp32 -> Wt [N][K] bf16. 64x64 tiles, 256 threads.
// ---------------------------------------------------------------------------
__global__ __launch_bounds__(256) void transpose_w(
    const float* __restrict__ W, u16* __restrict__ Wt, int K, int N)
{
  __shared__ float T[64][65];
  const int t = threadIdx.x;
  const int n0 = blockIdx.x * 64, k0 = blockIdx.y * 64;
  const int r = t >> 4, c4 = (t & 15) * 4;
  #pragma unroll
  for (int i = 0; i < 4; ++i) {
    f32x4 v = *(const f32x4*)&W[(size_t)(k0 + r + i * 16) * N + n0 + c4];
    T[r + i * 16][c4 + 0] = v.x;
    T[r + i * 16][c4 + 1] = v.y;
    T[r + i * 16][c4 + 2] = v.z;
    T[r + i * 16][c4 + 3] = v.w;
  }
  __syncthreads();
  const int nr = t >> 2, cs = (t & 3) * 16;
  u16x8 h0, h1;
  #pragma unroll
  for (int j = 0; j < 8; ++j) h0[j] = f2bf(T[cs + j][nr]);
  #pragma unroll
  for (int j = 0; j < 8; ++j) h1[j] = f2bf(T[cs + 8 + j][nr]);
  u16* dst = Wt + (size_t)(n0 + nr) * K + k0 + cs;
  *(u16x8*)dst = h0;
  *(u16x8*)(dst + 8) = h1;
}

// ---------------------------------------------------------------------------
// Kernel: QKV GEMM (m97 structure). Xb[8192][1024] bf16 @ Wqt[3072][1024]^T
// 128x128 tile, BK=32, 4 waves (2x2), global_load_lds staging, linear LDS.
// Epilogue: +bias, scatter bf16 to Q/K/V [B*H][N][64].
// ---------------------------------------------------------------------------
__global__ __launch_bounds__(256, 2) void qkv_gemm2(
    const u16* __restrict__ Xb, const u16* __restrict__ Wt,
    const float* __restrict__ bias,
    u16* __restrict__ Qb, u16* __restrict__ Kb, u16* __restrict__ Vb)
{
  constexpr int KD = 1024;
  __shared__ __align__(16) u16 As[128 * 32];
  __shared__ __align__(16) u16 Bs[128 * 32];

  const int tid = threadIdx.x;
  const int lane = tid & 63, wid = tid >> 6;
  const int wr = wid >> 1, wc = wid & 1;
  const int lg = lane >> 4, lc = lane & 15;
  const int row0 = blockIdx.x * 128, col0 = blockIdx.y * 128;

  f32x4 acc[4][4];
  #pragma unroll
  for (int m = 0; m < 4; ++m)
    #pragma unroll
    for (int n = 0; n < 4; ++n) acc[m][n] = (f32x4){0.f, 0.f, 0.f, 0.f};

  // staging geometry: chunk c in {wid, wid+4}; chunk covers rows c*16..+15,
  // lane covers row c*16 + lane/4, k-seg (lane%4)*8  (16B per lane, linear)
  const int l4 = lane >> 2, ls = (lane & 3) * 8;
  const u16* gA0 = Xb + (size_t)(row0 + wid * 16 + l4) * KD + ls;
  const u16* gB0 = Wt + (size_t)(col0 + wid * 16 + l4) * KD + ls;
  u16* lA0 = As + wid * 512;
  u16* lB0 = Bs + wid * 512;

  for (int k0 = 0; k0 < KD; k0 += 32) {
    gload16(gA0 + k0, lA0, lane);
    gload16(gA0 + 64 * KD + k0, lA0 + 2048, lane);
    gload16(gB0 + k0, lB0, lane);
    gload16(gB0 + 64 * KD + k0, lB0 + 2048, lane);
    __syncthreads();

    bf16x8 a[4], b[4];
    #pragma unroll
    for (int m = 0; m < 4; ++m)
      a[m] = *(const bf16x8*)(As + (wr * 64 + m * 16 + lc) * 32 + lg * 8);
    #pragma unroll
    for (int n = 0; n < 4; ++n)
      b[n] = *(const bf16x8*)(Bs + (wc * 64 + n * 16 + lc) * 32 + lg * 8);
    #pragma unroll
    for (int m = 0; m < 4; ++m)
      #pragma unroll
      for (int n = 0; n < 4; ++n)
        acc[m][n] = __builtin_amdgcn_mfma_f32_16x16x32_bf16(a[m], b[n], acc[m][n], 0, 0, 0);
    __syncthreads();
  }

  #pragma unroll
  for (int m = 0; m < 4; ++m) {
    #pragma unroll
    for (int n = 0; n < 4; ++n) {
      #pragma unroll
      for (int r = 0; r < 4; ++r) {
        int gr = row0 + wr * 64 + m * 16 + lg * 4 + r;   // [0,8192)
        int gc = col0 + wc * 64 + n * 16 + lc;           // [0,3072)
        float val = acc[m][n][r] + bias[gc];
        int which = gc >> 10, ci = gc & 1023;
        int h = ci >> 6, d = ci & 63;
        int bb = gr >> 10, nn = gr & 1023;
        u16* dst = (which == 0) ? Qb : (which == 1) ? Kb : Vb;
        dst[((size_t)(bb * 16 + h) * 1024 + nn) * 64 + d] = f2bf(val);
      }
    }
  }
}

// ---------------------------------------------------------------------------
// Kernel: flash attention (unchanged from round 1).
// ---------------------------------------------------------------------------
__global__ __launch_bounds__(256, 2) void attn_kernel(
    const u16* __restrict__ Q, const u16* __restrict__ K,
    const u16* __restrict__ V, u16* __restrict__ O)
{
  __shared__ u16 Ks[64][72];       // [key][d]
  __shared__ u16 Vt[64][72];       // [d][key]
  __shared__ u16 Pl[4][16][72];    // per-wave P [qrow][key]

  const int tid = threadIdx.x, lane = tid & 63, wid = tid >> 6;
  const int lg = lane >> 4, lc = lane & 15;
  const int qt = blockIdx.x;       // q tile [0,16)
  const int bh = blockIdx.y;       // b*16+h [0,128)
  const size_t base = (size_t)bh * 1024 * 64;
  const u16* Qp = Q + base;
  const u16* Kp = K + base;
  const u16* Vp = V + base;

  bf16x8 qf[2];
  {
    const u16* qsrc = Qp + (size_t)(qt * 64 + wid * 16 + lc) * 64 + lg * 8;
    #pragma unroll
    for (int ks = 0; ks < 2; ++ks) {
      u16x8 raw = *(const u16x8*)(qsrc + ks * 32);
      bf16x8 t;
      #pragma unroll
      for (int j = 0; j < 8; ++j) t[j] = (short)f2bf(bf2f(raw[j]) * 0.125f);
      qf[ks] = t;
    }
  }

  f32x4 o[4];
  #pragma unroll
  for (int fd = 0; fd < 4; ++fd) o[fd] = (f32x4){0.f, 0.f, 0.f, 0.f};
  float m_r[4] = {-1e30f, -1e30f, -1e30f, -1e30f};
  float l_r[4] = {0.f, 0.f, 0.f, 0.f};

  const int skr = tid >> 2, sds = (tid & 3) * 16;

  for (int kt = 0; kt < 16; ++kt) {
    const u16* ksrc = Kp + (size_t)(kt * 64 + skr) * 64 + sds;
    u16x8 ka = *(const u16x8*)ksrc, kb2 = *(const u16x8*)(ksrc + 8);
    *(u16x8*)&Ks[skr][sds]     = ka;
    *(u16x8*)&Ks[skr][sds + 8] = kb2;
    const u16* vsrc = Vp + (size_t)(kt * 64 + skr) * 64 + sds;
    u16x8 va = *(const u16x8*)vsrc, vb = *(const u16x8*)(vsrc + 8);
    #pragma unroll
    for (int j = 0; j < 8; ++j) {
      Vt[sds + j][skr]     = va[j];
      Vt[sds + 8 + j][skr] = vb[j];
    }
    __syncthreads();

    f32x4 s[4];
    #pragma unroll
    for (int kb = 0; kb < 4; ++kb) {
      s[kb] = (f32x4){0.f, 0.f, 0.f, 0.f};
      #pragma unroll
      for (int ks = 0; ks < 2; ++ks) {
        bf16x8 kf = *(const bf16x8*)&Ks[kb * 16 + lc][ks * 32 + lg * 8];
        s[kb] = __builtin_amdgcn_mfma_f32_16x16x32_bf16(qf[ks], kf, s[kb], 0, 0, 0);
      }
    }

    #pragma unroll
    for (int r = 0; r < 4; ++r) {
      float t = fmaxf(fmaxf(s[0][r], s[1][r]), fmaxf(s[2][r], s[3][r]));
      #pragma unroll
      for (int off = 8; off >= 1; off >>= 1) t = fmaxf(t, __shfl_xor(t, off));
      float nm = fmaxf(m_r[r], t);
      float sc = __expf(m_r[r] - nm);
      m_r[r] = nm;
      l_r[r] *= sc;
      #pragma unroll
      for (int fd = 0; fd < 4; ++fd) o[fd][r] *= sc;
    }
    #pragma unroll
    for (int kb = 0; kb < 4; ++kb) {
      #pragma unroll
      for (int r = 0; r < 4; ++r) {
        float p = __expf(s[kb][r] - m_r[r]);
        l_r[r] += p;
        Pl[wid][lg * 4 + r][lc + kb * 16] = f2bf(p);
      }
    }

    bf16x8 pa[2];
    #pragma unroll
    for (int ks = 0; ks < 2; ++ks)
      pa[ks] = *(const bf16x8*)&Pl[wid][lc][ks * 32 + lg * 8];
    #pragma unroll
    for (int fd = 0; fd < 4; ++fd) {
      #pragma unroll
      for (int ks = 0; ks < 2; ++ks) {
        bf16x8 vf = *(const bf16x8*)&Vt[fd * 16 + lc][ks * 32 + lg * 8];
        o[fd] = __builtin_amdgcn_mfma_f32_16x16x32_bf16(pa[ks], vf, o[fd], 0, 0, 0);
      }
    }
    __syncthreads();
  }

  #pragma unroll
  for (int r = 0; r < 4; ++r) {
    float t = l_r[r];
    #pragma unroll
    for (int off = 8; off >= 1; off >>= 1) t += __shfl_xor(t, off);
    l_r[r] = 1.0f / t;
  }
  const int b = bh >> 4, h = bh & 15;
  #pragma unroll
  for (int fd = 0; fd < 4; ++fd) {
    #pragma unroll
    for (int r = 0; r < 4; ++r) {
      int n = qt * 64 + wid * 16 + lg * 4 + r;
      O[((size_t)b * 1024 + n) * 1024 + h * 64 + fd * 16 + lc] =
          f2bf(o[fd][r] * l_r[r]);
    }
  }
}

// ---------------------------------------------------------------------------
// Kernel: projection GEMM (m97 structure). Ab[8192][1024] bf16 @ Wpt[1024][1024]^T
// -> fp32 out + bias.
// ---------------------------------------------------------------------------
__global__ __launch_bounds__(256, 2) void proj_gemm2(
    const u16* __restrict__ Ab, const u16* __restrict__ Wt,
    const float* __restrict__ bias, float* __restrict__ Out)
{
  constexpr int KD = 1024, NCOL = 1024;
  __shared__ __align__(16) u16 As[128 * 32];
  __shared__ __align__(16) u16 Bs[128 * 32];

  const int tid = threadIdx.x;
  const int lane = tid & 63, wid = tid >> 6;
  const int wr = wid >> 1, wc = wid & 1;
  const int lg = lane >> 4, lc = lane & 15;
  const int row0 = blockIdx.x * 128, col0 = blockIdx.y * 128;

  f32x4 acc[4][4];
  #pragma unroll
  for (int m = 0; m < 4; ++m)
    #pragma unroll
    for (int n = 0; n < 4; ++n) acc[m][n] = (f32x4){0.f, 0.f, 0.f, 0.f};

  const int l4 = lane >> 2, ls = (lane & 3) * 8;
  const u16* gA0 = Ab + (size_t)(row0 + wid * 16 + l4) * KD + ls;
  const u16* gB0 = Wt + (size_t)(col0 + wid * 16 + l4) * KD + ls;
  u16* lA0 = As + wid * 512;
  u16* lB0 = Bs + wid * 512;

  for (int k0 = 0; k0 < KD; k0 += 32) {
    gload16(gA0 + k0, lA0, lane);
    gload16(gA0 + 64 * KD + k0, lA0 + 2048, lane);
    gload16(gB0 + k0, lB0, lane);
    gload16(gB0 + 64 * KD + k0, lB0 + 2048, lane);
    __syncthreads();

    bf16x8 a[4], b[4];
    #pragma unroll
    for (int m = 0; m < 4; ++m)
      a[m] = *(const bf16x8*)(As + (wr * 64 + m * 16 + lc) * 32 + lg * 8);
    #pragma unroll
    for (int n = 0; n < 4; ++n)
      b[n] = *(const bf16x8*)(Bs + (wc * 64 + n * 16 + lc) * 32 + lg * 8);
    #pragma unroll
    for (int m = 0; m < 4; ++m)
      #pragma unroll
      for (int n = 0; n < 4; ++n)
        acc[m][n] = __builtin_amdgcn_mfma_f32_16x16x32_bf16(a[m], b[n], acc[m][n], 0, 0, 0);
    __syncthreads();
  }

  #pragma unroll
  for (int m = 0; m < 4; ++m) {
    #pragma unroll
    for (int n = 0; n < 4; ++n) {
      #pragma unroll
      for (int r = 0; r < 4; ++r) {
        int gr = row0 + wr * 64 + m * 16 + lg * 4 + r;
        int gc = col0 + wc * 64 + n * 16 + lc;
        Out[(size_t)gr * NCOL + gc] = acc[m][n][r] + bias[gc];
      }
    }
  }
}

// ---------------------------------------------------------------------------
extern "C" void kernel_launch(void* const* d_in, const int* in_sizes, int n_in,
                              void* d_out, int out_size, void* d_ws, size_t ws_size,
                              hipStream_t stream) {
  const float* x     = (const float*)d_in[0];
  const float* W_qkv = (const float*)d_in[1];
  const float* b_qkv = (const float*)d_in[2];
  const float* W_prj = (const float*)d_in[3];
  const float* b_prj = (const float*)d_in[4];
  float* out = (float*)d_out;

  const size_t SEG = (size_t)8192 * 1024;   // 8388608 elems (u16)
  char* ws = (char*)d_ws;
  u16* Xb  = (u16*)ws;                       // [0, 16.78M)  -- dead after qkv
  u16* Ab  = Xb;                             // alias: attn output
  u16* Vb  = (u16*)(ws + SEG * 2);           // [16.78M, 33.55M)
  u16* Wqt = (u16*)(ws + SEG * 4);           // [33.55M, 39.85M)
  u16* Wpt = Wqt + (size_t)3072 * 1024;      // [39.85M, 41.94M)
  u16* Qb  = (u16*)d_out;                    // d_out as scratch (overwritten by proj)
  u16* Kb  = Qb + SEG;

  convert_f32_bf16<<<4096, 256, 0, stream>>>(x, Xb);
  transpose_w<<<dim3(48, 16), 256, 0, stream>>>(W_qkv, Wqt, 1024, 3072);
  transpose_w<<<dim3(16, 16), 256, 0, stream>>>(W_prj, Wpt, 1024, 1024);
  qkv_gemm2<<<dim3(64, 24), 256, 0, stream>>>(Xb, Wqt, b_qkv, Qb, Kb, Vb);
  attn_kernel<<<dim3(16, 128), 256, 0, stream>>>(Qb, Kb, Vb, Ab);
  proj_gemm2<<<dim3(64, 8), 256, 0, stream>>>(Ab, Wpt, b_prj, out);
}

// Round 3
// 186.191 us; speedup vs baseline: 1.7589x; 1.1898x over previous
//
#include <hip/hip_runtime.h>
#include <hip/hip_bf16.h>

// Fused WindowAttention: x @ W_qkv + b -> MHA(16 heads, D=64) -> @ W_proj + b
// B=8, N=1024, C=1024. fp32 in/out; internal bf16 MFMA + fp32 accum.
//
// Pipeline:
//   1. convert_f32_bf16 : X fp32 -> Xb bf16
//   2. transpose_w x2   : W_qkv -> Wqt [3072][1024] bf16, W_proj -> Wpt bf16
//   3. qkv_gemm2 (m97-style, global_load_lds) -> Q/K/V bf16 [B*H][N][64]
//   4. attn_kernel v2: swapped QK^T, 128-q blocks, swizzled V^T
//   5. proj_gemm2 (m97-style)                -> fp32 d_out

using bf16x8 = __attribute__((ext_vector_type(8))) short;
using f32x4  = __attribute__((ext_vector_type(4))) float;
using u16    = unsigned short;
using u16x8  = __attribute__((ext_vector_type(8))) unsigned short;

__device__ __forceinline__ u16 f2bf(float f) {
  unsigned int u = __float_as_uint(f);
  u += 0x7FFFu + ((u >> 16) & 1u);   // RNE (finite inputs only)
  return (u16)(u >> 16);
}
__device__ __forceinline__ float bf2f(u16 h) {
  return __uint_as_float(((unsigned int)h) << 16);
}

__device__ __forceinline__ void gload16(const u16* g, u16* lbase, int lane) {
#if __has_builtin(__builtin_amdgcn_global_load_lds)
  __builtin_amdgcn_global_load_lds(
      (const __attribute__((address_space(1))) void*)g,
      (__attribute__((address_space(3))) void*)lbase, 16, 0, 0);
#else
  *(u16x8*)(lbase + (size_t)lane * 8) = *(const u16x8*)g;
#endif
}

// ---------------------------------------------------------------------------
__global__ __launch_bounds__(256) void convert_f32_bf16(
    const float* __restrict__ in, u16* __restrict__ out)
{
  size_t i = ((size_t)blockIdx.x * 256 + threadIdx.x) * 8;
  f32x4 a = *(const f32x4*)(in + i);
  f32x4 b = *(const f32x4*)(in + i + 4);
  u16x8 h = { f2bf(a.x), f2bf(a.y), f2bf(a.z), f2bf(a.w),
              f2bf(b.x), f2bf(b.y), f2bf(b.z), f2bf(b.w) };
  *(u16x8*)(out + i) = h;
}

// ---------------------------------------------------------------------------
__global__ __launch_bounds__(256) void transpose_w(
    const float* __restrict__ W, u16* __restrict__ Wt, int K, int N)
{
  __shared__ float T[64][65];
  const int t = threadIdx.x;
  const int n0 = blockIdx.x * 64, k0 = blockIdx.y * 64;
  const int r = t >> 4, c4 = (t & 15) * 4;
  #pragma unroll
  for (int i = 0; i < 4; ++i) {
    f32x4 v = *(const f32x4*)&W[(size_t)(k0 + r + i * 16) * N + n0 + c4];
    T[r + i * 16][c4 + 0] = v.x;
    T[r + i * 16][c4 + 1] = v.y;
    T[r + i * 16][c4 + 2] = v.z;
    T[r + i * 16][c4 + 3] = v.w;
  }
  __syncthreads();
  const int nr = t >> 2, cs = (t & 3) * 16;
  u16x8 h0, h1;
  #pragma unroll
  for (int j = 0; j < 8; ++j) h0[j] = f2bf(T[cs + j][nr]);
  #pragma unroll
  for (int j = 0; j < 8; ++j) h1[j] = f2bf(T[cs + 8 + j][nr]);
  u16* dst = Wt + (size_t)(n0 + nr) * K + k0 + cs;
  *(u16x8*)dst = h0;
  *(u16x8*)(dst + 8) = h1;
}

// ---------------------------------------------------------------------------
// QKV GEMM (m97 structure), unchanged from round 2.
// ---------------------------------------------------------------------------
__global__ __launch_bounds__(256, 2) void qkv_gemm2(
    const u16* __restrict__ Xb, const u16* __restrict__ Wt,
    const float* __restrict__ bias,
    u16* __restrict__ Qb, u16* __restrict__ Kb, u16* __restrict__ Vb)
{
  constexpr int KD = 1024;
  __shared__ __align__(16) u16 As[128 * 32];
  __shared__ __align__(16) u16 Bs[128 * 32];

  const int tid = threadIdx.x;
  const int lane = tid & 63, wid = tid >> 6;
  const int wr = wid >> 1, wc = wid & 1;
  const int lg = lane >> 4, lc = lane & 15;
  const int row0 = blockIdx.x * 128, col0 = blockIdx.y * 128;

  f32x4 acc[4][4];
  #pragma unroll
  for (int m = 0; m < 4; ++m)
    #pragma unroll
    for (int n = 0; n < 4; ++n) acc[m][n] = (f32x4){0.f, 0.f, 0.f, 0.f};

  const int l4 = lane >> 2, ls = (lane & 3) * 8;
  const u16* gA0 = Xb + (size_t)(row0 + wid * 16 + l4) * KD + ls;
  const u16* gB0 = Wt + (size_t)(col0 + wid * 16 + l4) * KD + ls;
  u16* lA0 = As + wid * 512;
  u16* lB0 = Bs + wid * 512;

  for (int k0 = 0; k0 < KD; k0 += 32) {
    gload16(gA0 + k0, lA0, lane);
    gload16(gA0 + 64 * KD + k0, lA0 + 2048, lane);
    gload16(gB0 + k0, lB0, lane);
    gload16(gB0 + 64 * KD + k0, lB0 + 2048, lane);
    __syncthreads();

    bf16x8 a[4], b[4];
    #pragma unroll
    for (int m = 0; m < 4; ++m)
      a[m] = *(const bf16x8*)(As + (wr * 64 + m * 16 + lc) * 32 + lg * 8);
    #pragma unroll
    for (int n = 0; n < 4; ++n)
      b[n] = *(const bf16x8*)(Bs + (wc * 64 + n * 16 + lc) * 32 + lg * 8);
    #pragma unroll
    for (int m = 0; m < 4; ++m)
      #pragma unroll
      for (int n = 0; n < 4; ++n)
        acc[m][n] = __builtin_amdgcn_mfma_f32_16x16x32_bf16(a[m], b[n], acc[m][n], 0, 0, 0);
    __syncthreads();
  }

  #pragma unroll
  for (int m = 0; m < 4; ++m) {
    #pragma unroll
    for (int n = 0; n < 4; ++n) {
      #pragma unroll
      for (int r = 0; r < 4; ++r) {
        int gr = row0 + wr * 64 + m * 16 + lg * 4 + r;   // [0,8192)
        int gc = col0 + wc * 64 + n * 16 + lc;           // [0,3072)
        float val = acc[m][n][r] + bias[gc];
        int which = gc >> 10, ci = gc & 1023;
        int h = ci >> 6, d = ci & 63;
        int bb = gr >> 10, nn = gr & 1023;
        u16* dst = (which == 0) ? Qb : (which == 1) ? Kb : Vb;
        dst[((size_t)(bb * 16 + h) * 1024 + nn) * 64 + d] = f2bf(val);
      }
    }
  }
}

// ---------------------------------------------------------------------------
// Flash attention v2. Block = 128 q-rows of one (b,h); 4 waves x 32 rows.
// Swapped QK^T (mfma(K,Q)) -> per-lane q-row stats; P via packed-u32 per-wave
// LDS; V^T staged with XOR swizzle (conflict-free writes).
// ---------------------------------------------------------------------------
__global__ __launch_bounds__(256, 2) void attn_kernel(
    const u16* __restrict__ Q, const u16* __restrict__ K,
    const u16* __restrict__ V, u16* __restrict__ O)
{
  __shared__ __align__(16) u16 Ks[64 * 72];       // [key][d] stride 72
  __shared__ __align__(16) u16 Vt[64 * 72];       // [d][key^swz] stride 72
  __shared__ __align__(16) u16 Pl[4 * 32 * 72];   // per-wave [qrow][key]

  const int tid = threadIdx.x, lane = tid & 63, wid = tid >> 6;
  const int lg = lane >> 4, lc = lane & 15;
  const int qt = blockIdx.x;       // q tile of 128 rows [0,8)
  const int bh = blockIdx.y;       // [0,128)
  const size_t base = (size_t)bh * 1024 * 64;
  const u16* Qp = Q + base;
  const u16* Kp = K + base;
  const u16* Vp = V + base;

  // Q fragments (B-operand): rows qt*128 + wid*32 + f*16 + lc, pre-scaled
  bf16x8 qf[2][2];
  #pragma unroll
  for (int f = 0; f < 2; ++f) {
    const u16* qsrc = Qp + (size_t)(qt * 128 + wid * 32 + f * 16 + lc) * 64 + lg * 8;
    #pragma unroll
    for (int ks = 0; ks < 2; ++ks) {
      u16x8 raw = *(const u16x8*)(qsrc + ks * 32);
      bf16x8 t;
      #pragma unroll
      for (int j = 0; j < 8; ++j) t[j] = (short)f2bf(bf2f(raw[j]) * 0.125f);
      qf[f][ks] = t;
    }
  }

  f32x4 o[2][4];
  #pragma unroll
  for (int f = 0; f < 2; ++f)
    #pragma unroll
    for (int d = 0; d < 4; ++d) o[f][d] = (f32x4){0.f, 0.f, 0.f, 0.f};
  float m_r[2] = {-1e30f, -1e30f};
  float l_r[2] = {0.f, 0.f};

  // staging: thread -> key row (t>>2), d-seg (t&3)*16
  const int skr = tid >> 2;
  const int sd  = (tid & 3) * 16;
  const int vswz = (tid & 3) << 5;                 // byte xor for Vt rows sd..sd+15
  const int vcol = (((skr * 2) ^ vswz) >> 1);      // swizzled key column (elems)
  u16* kw = Ks + skr * 72 + sd;
  const int prow = (wid * 32 + lc) * 72;           // P row base for f=0

  for (int kt = 0; kt < 16; ++kt) {
    const u16* ksrc = Kp + (size_t)(kt * 64 + skr) * 64 + sd;
    u16x8 k0 = *(const u16x8*)ksrc, k1 = *(const u16x8*)(ksrc + 8);
    *(u16x8*)kw = k0;
    *(u16x8*)(kw + 8) = k1;
    const u16* vsrc = Vp + (size_t)(kt * 64 + skr) * 64 + sd;
    u16x8 v0 = *(const u16x8*)vsrc, v1 = *(const u16x8*)(vsrc + 8);
    #pragma unroll
    for (int j = 0; j < 8; ++j) {
      Vt[(sd + j) * 72 + vcol]     = v0[j];
      Vt[(sd + 8 + j) * 72 + vcol] = v1[j];
    }
    __syncthreads();

    // S^T = K @ Q : s[f][kb], lane holds q-row (f*16+lc), keys kb*16+lg*4+r
    f32x4 s[2][4];
    #pragma unroll
    for (int f = 0; f < 2; ++f)
      #pragma unroll
      for (int kb = 0; kb < 4; ++kb) s[f][kb] = (f32x4){0.f, 0.f, 0.f, 0.f};
    #pragma unroll
    for (int ks = 0; ks < 2; ++ks) {
      #pragma unroll
      for (int kb = 0; kb < 4; ++kb) {
        bf16x8 kf = *(const bf16x8*)(Ks + (kb * 16 + lc) * 72 + ks * 32 + lg * 8);
        s[0][kb] = __builtin_amdgcn_mfma_f32_16x16x32_bf16(kf, qf[0][ks], s[0][kb], 0, 0, 0);
        s[1][kb] = __builtin_amdgcn_mfma_f32_16x16x32_bf16(kf, qf[1][ks], s[1][kb], 0, 0, 0);
      }
    }

    // online softmax, P pack+store (per-wave LDS, no barrier needed)
    #pragma unroll
    for (int f = 0; f < 2; ++f) {
      f32x4 t01, t23;
      #pragma unroll
      for (int c = 0; c < 4; ++c) {
        t01[c] = fmaxf(s[f][0][c], s[f][1][c]);
        t23[c] = fmaxf(s[f][2][c], s[f][3][c]);
      }
      float t = fmaxf(fmaxf(fmaxf(t01[0], t01[1]), fmaxf(t01[2], t01[3])),
                      fmaxf(fmaxf(t23[0], t23[1]), fmaxf(t23[2], t23[3])));
      t = fmaxf(t, __shfl_xor(t, 16));
      t = fmaxf(t, __shfl_xor(t, 32));
      float nm = fmaxf(m_r[f], t);
      float sc = __expf(m_r[f] - nm);
      m_r[f] = nm;

      float lsum = 0.f;
      #pragma unroll
      for (int kb = 0; kb < 4; ++kb) {
        f32x4 p;
        #pragma unroll
        for (int c = 0; c < 4; ++c) {
          p[c] = __expf(s[f][kb][c] - nm);
          lsum += p[c];
        }
        unsigned w0 = (unsigned)f2bf(p[0]) | ((unsigned)f2bf(p[1]) << 16);
        unsigned w1 = (unsigned)f2bf(p[2]) | ((unsigned)f2bf(p[3]) << 16);
        int pe = prow + f * 16 * 72 + kb * 16 + lg * 4;
        *(unsigned*)(Pl + pe)     = w0;
        *(unsigned*)(Pl + pe + 2) = w1;
      }
      lsum += __shfl_xor(lsum, 16);
      lsum += __shfl_xor(lsum, 32);
      l_r[f] = l_r[f] * sc + lsum;

      // rescale O rows (row = lg*4+r; scale lives at lane lc=row)
      #pragma unroll
      for (int r = 0; r < 4; ++r) {
        float scr = __shfl(sc, lg * 4 + r, 16);
        #pragma unroll
        for (int d = 0; d < 4; ++d) o[f][d][r] *= scr;
      }
    }

    // drain P writes (in-order DS per wave; fence vs compiler reordering)
    asm volatile("s_waitcnt lgkmcnt(0)" ::: "memory");
    __builtin_amdgcn_sched_barrier(0);

    // PV: O += P @ V^T-frags
    bf16x8 pa[2][2];
    #pragma unroll
    for (int f = 0; f < 2; ++f)
      #pragma unroll
      for (int ks = 0; ks < 2; ++ks)
        pa[f][ks] = *(const bf16x8*)(Pl + prow + f * 16 * 72 + ks * 32 + lg * 8);
    #pragma unroll
    for (int d = 0; d < 4; ++d) {
      #pragma unroll
      for (int ks = 0; ks < 2; ++ks) {
        bf16x8 vf = *(const bf16x8*)(Vt + (d * 16 + lc) * 72 +
                                     (((ks * 64 + lg * 16) ^ (d << 5)) >> 1));
        o[0][d] = __builtin_amdgcn_mfma_f32_16x16x32_bf16(pa[0][ks], vf, o[0][d], 0, 0, 0);
        o[1][d] = __builtin_amdgcn_mfma_f32_16x16x32_bf16(pa[1][ks], vf, o[1][d], 0, 0, 0);
      }
    }
    __syncthreads();
  }

  // finalize + store bf16 [B][N][C]
  const int b = bh >> 4, h = bh & 15;
  #pragma unroll
  for (int f = 0; f < 2; ++f) {
    float linv = 1.0f / l_r[f];
    #pragma unroll
    for (int r = 0; r < 4; ++r) {
      float li = __shfl(linv, lg * 4 + r, 16);
      int n = qt * 128 + wid * 32 + f * 16 + lg * 4 + r;
      u16* dst = O + ((size_t)b * 1024 + n) * 1024 + h * 64 + lc;
      #pragma unroll
      for (int d = 0; d < 4; ++d) dst[d * 16] = f2bf(o[f][d][r] * li);
    }
  }
}

// ---------------------------------------------------------------------------
// Projection GEMM (m97 structure), unchanged from round 2.
// ---------------------------------------------------------------------------
__global__ __launch_bounds__(256, 2) void proj_gemm2(
    const u16* __restrict__ Ab, const u16* __restrict__ Wt,
    const float* __restrict__ bias, float* __restrict__ Out)
{
  constexpr int KD = 1024, NCOL = 1024;
  __shared__ __align__(16) u16 As[128 * 32];
  __shared__ __align__(16) u16 Bs[128 * 32];

  const int tid = threadIdx.x;
  const int lane = tid & 63, wid = tid >> 6;
  const int wr = wid >> 1, wc = wid & 1;
  const int lg = lane >> 4, lc = lane & 15;
  const int row0 = blockIdx.x * 128, col0 = blockIdx.y * 128;

  f32x4 acc[4][4];
  #pragma unroll
  for (int m = 0; m < 4; ++m)
    #pragma unroll
    for (int n = 0; n < 4; ++n) acc[m][n] = (f32x4){0.f, 0.f, 0.f, 0.f};

  const int l4 = lane >> 2, ls = (lane & 3) * 8;
  const u16* gA0 = Ab + (size_t)(row0 + wid * 16 + l4) * KD + ls;
  const u16* gB0 = Wt + (size_t)(col0 + wid * 16 + l4) * KD + ls;
  u16* lA0 = As + wid * 512;
  u16* lB0 = Bs + wid * 512;

  for (int k0 = 0; k0 < KD; k0 += 32) {
    gload16(gA0 + k0, lA0, lane);
    gload16(gA0 + 64 * KD + k0, lA0 + 2048, lane);
    gload16(gB0 + k0, lB0, lane);
    gload16(gB0 + 64 * KD + k0, lB0 + 2048, lane);
    __syncthreads();

    bf16x8 a[4], b[4];
    #pragma unroll
    for (int m = 0; m < 4; ++m)
      a[m] = *(const bf16x8*)(As + (wr * 64 + m * 16 + lc) * 32 + lg * 8);
    #pragma unroll
    for (int n = 0; n < 4; ++n)
      b[n] = *(const bf16x8*)(Bs + (wc * 64 + n * 16 + lc) * 32 + lg * 8);
    #pragma unroll
    for (int m = 0; m < 4; ++m)
      #pragma unroll
      for (int n = 0; n < 4; ++n)
        acc[m][n] = __builtin_amdgcn_mfma_f32_16x16x32_bf16(a[m], b[n], acc[m][n], 0, 0, 0);
    __syncthreads();
  }

  #pragma unroll
  for (int m = 0; m < 4; ++m) {
    #pragma unroll
    for (int n = 0; n < 4; ++n) {
      #pragma unroll
      for (int r = 0; r < 4; ++r) {
        int gr = row0 + wr * 64 + m * 16 + lg * 4 + r;
        int gc = col0 + wc * 64 + n * 16 + lc;
        Out[(size_t)gr * NCOL + gc] = acc[m][n][r] + bias[gc];
      }
    }
  }
}

// ---------------------------------------------------------------------------
extern "C" void kernel_launch(void* const* d_in, const int* in_sizes, int n_in,
                              void* d_out, int out_size, void* d_ws, size_t ws_size,
                              hipStream_t stream) {
  const float* x     = (const float*)d_in[0];
  const float* W_qkv = (const float*)d_in[1];
  const float* b_qkv = (const float*)d_in[2];
  const float* W_prj = (const float*)d_in[3];
  const float* b_prj = (const float*)d_in[4];
  float* out = (float*)d_out;

  const size_t SEG = (size_t)8192 * 1024;   // 8388608 elems (u16)
  char* ws = (char*)d_ws;
  u16* Xb  = (u16*)ws;                       // dead after qkv
  u16* Ab  = Xb;                             // alias: attn output
  u16* Vb  = (u16*)(ws + SEG * 2);
  u16* Wqt = (u16*)(ws + SEG * 4);
  u16* Wpt = Wqt + (size_t)3072 * 1024;
  u16* Qb  = (u16*)d_out;                    // d_out as scratch
  u16* Kb  = Qb + SEG;

  convert_f32_bf16<<<4096, 256, 0, stream>>>(x, Xb);
  transpose_w<<<dim3(48, 16), 256, 0, stream>>>(W_qkv, Wqt, 1024, 3072);
  transpose_w<<<dim3(16, 16), 256, 0, stream>>>(W_prj, Wpt, 1024, 1024);
  qkv_gemm2<<<dim3(64, 24), 256, 0, stream>>>(Xb, Wqt, b_qkv, Qb, Kb, Vb);
  attn_kernel<<<dim3(8, 128), 256, 0, stream>>>(Qb, Kb, Vb, Ab);
  proj_gemm2<<<dim3(64, 8), 256, 0, stream>>>(Ab, Wpt, b_prj, out);
}

// Round 4
// 171.320 us; speedup vs baseline: 1.9116x; 1.0868x over previous
//
#include <hip/hip_runtime.h>
#include <hip/hip_bf16.h>

// Fused WindowAttention: x @ W_qkv + b -> MHA(16 heads, D=64) -> @ W_proj + b
// B=8, N=1024, C=1024. fp32 in/out; internal bf16 MFMA + fp32 accum.
//
// Pipeline:
//   1. convert_f32_bf16 : X fp32 -> Xb bf16
//   2. transpose_w x2   : W_qkv -> Wqt [3072][1024] bf16, W_proj -> Wpt bf16
//   3. qkv_gemm2 -> Q,K bf16 [B*H][N][64]; V stored TRANSPOSED [B*H][64][N]
//   4. attn_kernel v3: swapped QK^T, global_load_lds K/V^T staging with
//      pre-swizzled source, XCD-local grid, defer-max
//   5. proj_gemm2 -> fp32 d_out

using bf16x8 = __attribute__((ext_vector_type(8))) short;
using f32x4  = __attribute__((ext_vector_type(4))) float;
using u16    = unsigned short;
using u16x4  = __attribute__((ext_vector_type(4))) unsigned short;
using u16x8  = __attribute__((ext_vector_type(8))) unsigned short;

__device__ __forceinline__ u16 f2bf(float f) {
  unsigned int u = __float_as_uint(f);
  u += 0x7FFFu + ((u >> 16) & 1u);   // RNE (finite inputs only)
  return (u16)(u >> 16);
}
__device__ __forceinline__ float bf2f(u16 h) {
  return __uint_as_float(((unsigned int)h) << 16);
}

__device__ __forceinline__ void gload16(const u16* g, u16* lbase, int lane) {
#if __has_builtin(__builtin_amdgcn_global_load_lds)
  __builtin_amdgcn_global_load_lds(
      (const __attribute__((address_space(1))) void*)g,
      (__attribute__((address_space(3))) void*)lbase, 16, 0, 0);
#else
  *(u16x8*)(lbase + (size_t)lane * 8) = *(const u16x8*)g;
#endif
}

// ---------------------------------------------------------------------------
__global__ __launch_bounds__(256) void convert_f32_bf16(
    const float* __restrict__ in, u16* __restrict__ out)
{
  size_t i = ((size_t)blockIdx.x * 256 + threadIdx.x) * 8;
  f32x4 a = *(const f32x4*)(in + i);
  f32x4 b = *(const f32x4*)(in + i + 4);
  u16x8 h = { f2bf(a.x), f2bf(a.y), f2bf(a.z), f2bf(a.w),
              f2bf(b.x), f2bf(b.y), f2bf(b.z), f2bf(b.w) };
  *(u16x8*)(out + i) = h;
}

// ---------------------------------------------------------------------------
__global__ __launch_bounds__(256) void transpose_w(
    const float* __restrict__ W, u16* __restrict__ Wt, int K, int N)
{
  __shared__ float T[64][65];
  const int t = threadIdx.x;
  const int n0 = blockIdx.x * 64, k0 = blockIdx.y * 64;
  const int r = t >> 4, c4 = (t & 15) * 4;
  #pragma unroll
  for (int i = 0; i < 4; ++i) {
    f32x4 v = *(const f32x4*)&W[(size_t)(k0 + r + i * 16) * N + n0 + c4];
    T[r + i * 16][c4 + 0] = v.x;
    T[r + i * 16][c4 + 1] = v.y;
    T[r + i * 16][c4 + 2] = v.z;
    T[r + i * 16][c4 + 3] = v.w;
  }
  __syncthreads();
  const int nr = t >> 2, cs = (t & 3) * 16;
  u16x8 h0, h1;
  #pragma unroll
  for (int j = 0; j < 8; ++j) h0[j] = f2bf(T[cs + j][nr]);
  #pragma unroll
  for (int j = 0; j < 8; ++j) h1[j] = f2bf(T[cs + 8 + j][nr]);
  u16* dst = Wt + (size_t)(n0 + nr) * K + k0 + cs;
  *(u16x8*)dst = h0;
  *(u16x8*)(dst + 8) = h1;
}

// ---------------------------------------------------------------------------
// QKV GEMM (m97 structure). Q,K -> [bh][n][64]; V -> TRANSPOSED [bh][64][n].
// ---------------------------------------------------------------------------
__global__ __launch_bounds__(256, 2) void qkv_gemm2(
    const u16* __restrict__ Xb, const u16* __restrict__ Wt,
    const float* __restrict__ bias,
    u16* __restrict__ Qb, u16* __restrict__ Kb, u16* __restrict__ VtG)
{
  constexpr int KD = 1024;
  __shared__ __align__(16) u16 As[128 * 32];
  __shared__ __align__(16) u16 Bs[128 * 32];

  const int tid = threadIdx.x;
  const int lane = tid & 63, wid = tid >> 6;
  const int wr = wid >> 1, wc = wid & 1;
  const int lg = lane >> 4, lc = lane & 15;
  const int row0 = blockIdx.x * 128, col0 = blockIdx.y * 128;

  f32x4 acc[4][4];
  #pragma unroll
  for (int m = 0; m < 4; ++m)
    #pragma unroll
    for (int n = 0; n < 4; ++n) acc[m][n] = (f32x4){0.f, 0.f, 0.f, 0.f};

  const int l4 = lane >> 2, ls = (lane & 3) * 8;
  const u16* gA0 = Xb + (size_t)(row0 + wid * 16 + l4) * KD + ls;
  const u16* gB0 = Wt + (size_t)(col0 + wid * 16 + l4) * KD + ls;
  u16* lA0 = As + wid * 512;
  u16* lB0 = Bs + wid * 512;

  for (int k0 = 0; k0 < KD; k0 += 32) {
    gload16(gA0 + k0, lA0, lane);
    gload16(gA0 + 64 * KD + k0, lA0 + 2048, lane);
    gload16(gB0 + k0, lB0, lane);
    gload16(gB0 + 64 * KD + k0, lB0 + 2048, lane);
    __syncthreads();

    bf16x8 a[4], b[4];
    #pragma unroll
    for (int m = 0; m < 4; ++m)
      a[m] = *(const bf16x8*)(As + (wr * 64 + m * 16 + lc) * 32 + lg * 8);
    #pragma unroll
    for (int n = 0; n < 4; ++n)
      b[n] = *(const bf16x8*)(Bs + (wc * 64 + n * 16 + lc) * 32 + lg * 8);
    #pragma unroll
    for (int m = 0; m < 4; ++m)
      #pragma unroll
      for (int n = 0; n < 4; ++n)
        acc[m][n] = __builtin_amdgcn_mfma_f32_16x16x32_bf16(a[m], b[n], acc[m][n], 0, 0, 0);
    __syncthreads();
  }

  #pragma unroll
  for (int m = 0; m < 4; ++m) {
    #pragma unroll
    for (int n = 0; n < 4; ++n) {
      const int gcb = col0 + wc * 64 + n * 16;     // frag channel base (uniform/wave)
      const int which = gcb >> 10;
      const int gc = gcb + lc;
      const float bv = bias[gc];
      const int ci = gc & 1023, h = ci >> 6, d = ci & 63;
      const int gr0 = row0 + wr * 64 + m * 16 + lg * 4;
      const int bb = gr0 >> 10, nn0 = gr0 & 1023;  // nn0 multiple of 4
      if (which == 2) {
        u16x4 pv = { f2bf(acc[m][n][0] + bv), f2bf(acc[m][n][1] + bv),
                     f2bf(acc[m][n][2] + bv), f2bf(acc[m][n][3] + bv) };
        *(u16x4*)&VtG[((size_t)(bb * 16 + h) * 64 + d) * 1024 + nn0] = pv;
      } else {
        u16* dst = (which == 0) ? Qb : Kb;
        #pragma unroll
        for (int r = 0; r < 4; ++r)
          dst[((size_t)(bb * 16 + h) * 1024 + nn0 + r) * 64 + d] =
              f2bf(acc[m][n][r] + bv);
      }
    }
  }
}

// ---------------------------------------------------------------------------
// Flash attention v3. Block = 128 q-rows of one (b,h); 4 waves x 32 rows.
// Grid (bh=128, qt=8): id%8 = bh%8 -> all q-tiles of a head on one XCD.
// K and V^T staged via global_load_lds, pre-swizzled source (slot ^= row&7),
// linear LDS [64][64]; reads apply the same XOR. Defer-max THR=8.
// ---------------------------------------------------------------------------
__global__ __launch_bounds__(256, 2) void attn_kernel(
    const u16* __restrict__ Q, const u16* __restrict__ K,
    const u16* __restrict__ Vt, u16* __restrict__ O)
{
  __shared__ __align__(16) u16 Ks[64 * 64];       // [key][d] swizzled slots
  __shared__ __align__(16) u16 Vs[64 * 64];       // [d][key] swizzled slots
  __shared__ __align__(16) u16 Pl[4 * 32 * 72];   // per-wave [qrow][key]

  const int tid = threadIdx.x, lane = tid & 63, wid = tid >> 6;
  const int lg = lane >> 4, lc = lane & 15;
  const int bh = blockIdx.x;       // [0,128)
  const int qt = blockIdx.y;       // [0,8)
  const size_t base = (size_t)bh * 65536;
  const u16* Qp = Q + base;
  const u16* Kp = K + base;
  const u16* Vp = Vt + base;       // [64][1024]

  // Q fragments (B-operand), pre-scaled by 0.125
  bf16x8 qf[2][2];
  #pragma unroll
  for (int f = 0; f < 2; ++f) {
    const u16* qsrc = Qp + (size_t)(qt * 128 + wid * 32 + f * 16 + lc) * 64 + lg * 8;
    #pragma unroll
    for (int ks = 0; ks < 2; ++ks) {
      u16x8 raw = *(const u16x8*)(qsrc + ks * 32);
      bf16x8 t;
      #pragma unroll
      for (int j = 0; j < 8; ++j) t[j] = (short)f2bf(bf2f(raw[j]) * 0.125f);
      qf[f][ks] = t;
    }
  }

  f32x4 o[2][4];
  #pragma unroll
  for (int f = 0; f < 2; ++f)
    #pragma unroll
    for (int d = 0; d < 4; ++d) o[f][d] = (f32x4){0.f, 0.f, 0.f, 0.f};
  float m_r[2] = {-1e30f, -1e30f};
  float l_r[2] = {0.f, 0.f};

  // staging: wave w stages rows [w*16, w*16+16) of each tile.
  // dest(row, slot16) holds logical[row][slot ^ (row&7)] (row&7 == lane>>3).
  const int srow  = lane >> 3;               // 0..7
  const int sslot = (lane & 7) ^ srow;       // pre-swizzled 16B slot
  const u16* gK0 = Kp + (size_t)(wid * 16 + srow) * 64 + sslot * 8;
  const u16* gV0 = Vp + (size_t)(wid * 16 + srow) * 1024 + sslot * 8;
  u16* lK0 = Ks + wid * 1024;
  u16* lV0 = Vs + wid * 1024;

  // read-side swizzled column offsets (elems): slot = ks*4+lg, xor row&7=lc&7
  const int xr = lc & 7;
  const int cof0 = ((0 + lg) ^ xr) * 8;
  const int cof1 = ((4 + lg) ^ xr) * 8;
  const int prow = (wid * 32 + lc) * 72;

  for (int kt = 0; kt < 16; ++kt) {
    gload16(gK0 + kt * 4096, lK0, lane);            // rows w*16..+8
    gload16(gK0 + kt * 4096 + 512, lK0 + 512, lane); // rows w*16+8..+16
    gload16(gV0 + kt * 64, lV0, lane);
    gload16(gV0 + 8192 + kt * 64, lV0 + 512, lane);
    __syncthreads();

    // S^T = K @ Q : lane holds q-row f*16+lc, keys kb*16 + lg*4 + c
    f32x4 s[2][4];
    #pragma unroll
    for (int f = 0; f < 2; ++f)
      #pragma unroll
      for (int kb = 0; kb < 4; ++kb) s[f][kb] = (f32x4){0.f, 0.f, 0.f, 0.f};
    #pragma unroll
    for (int ks = 0; ks < 2; ++ks) {
      const int co = ks ? cof1 : cof0;
      #pragma unroll
      for (int kb = 0; kb < 4; ++kb) {
        bf16x8 kfr = *(const bf16x8*)(Ks + (kb * 16 + lc) * 64 + co);
        s[0][kb] = __builtin_amdgcn_mfma_f32_16x16x32_bf16(kfr, qf[0][ks], s[0][kb], 0, 0, 0);
        s[1][kb] = __builtin_amdgcn_mfma_f32_16x16x32_bf16(kfr, qf[1][ks], s[1][kb], 0, 0, 0);
      }
    }

    // online softmax with defer-max; P pack+store to per-wave LDS
    #pragma unroll
    for (int f = 0; f < 2; ++f) {
      f32x4 t01, t23;
      #pragma unroll
      for (int c = 0; c < 4; ++c) {
        t01[c] = fmaxf(s[f][0][c], s[f][1][c]);
        t23[c] = fmaxf(s[f][2][c], s[f][3][c]);
      }
      float t = fmaxf(fmaxf(fmaxf(t01[0], t01[1]), fmaxf(t01[2], t01[3])),
                      fmaxf(fmaxf(t23[0], t23[1]), fmaxf(t23[2], t23[3])));
      t = fmaxf(t, __shfl_xor(t, 16));
      t = fmaxf(t, __shfl_xor(t, 32));

      if (!__all((t - m_r[f]) <= 8.0f)) {            // max grew: rescale
        float nm = fmaxf(m_r[f], t);
        float sc = __expf(m_r[f] - nm);
        m_r[f] = nm;
        l_r[f] *= sc;
        #pragma unroll
        for (int r = 0; r < 4; ++r) {
          float scr = __shfl(sc, lg * 4 + r, 16);
          #pragma unroll
          for (int d = 0; d < 4; ++d) o[f][d][r] *= scr;
        }
      }

      float lsum = 0.f;
      #pragma unroll
      for (int kb = 0; kb < 4; ++kb) {
        f32x4 p;
        #pragma unroll
        for (int c = 0; c < 4; ++c) {
          p[c] = __expf(s[f][kb][c] - m_r[f]);
          lsum += p[c];
        }
        unsigned w0 = (unsigned)f2bf(p[0]) | ((unsigned)f2bf(p[1]) << 16);
        unsigned w1 = (unsigned)f2bf(p[2]) | ((unsigned)f2bf(p[3]) << 16);
        int pe = prow + f * 16 * 72 + kb * 16 + lg * 4;
        *(unsigned*)(Pl + pe)     = w0;
        *(unsigned*)(Pl + pe + 2) = w1;
      }
      lsum += __shfl_xor(lsum, 16);
      lsum += __shfl_xor(lsum, 32);
      l_r[f] += lsum;
    }

    // drain P writes (same-wave LDS); fence compiler reordering
    asm volatile("s_waitcnt lgkmcnt(0)" ::: "memory");
    __builtin_amdgcn_sched_barrier(0);

    // PV: O += P @ V^T-frags
    bf16x8 pa[2][2];
    #pragma unroll
    for (int f = 0; f < 2; ++f)
      #pragma unroll
      for (int ks = 0; ks < 2; ++ks)
        pa[f][ks] = *(const bf16x8*)(Pl + prow + f * 16 * 72 + ks * 32 + lg * 8);
    #pragma unroll
    for (int d = 0; d < 4; ++d) {
      #pragma unroll
      for (int ks = 0; ks < 2; ++ks) {
        const int co = ks ? cof1 : cof0;
        bf16x8 vfr = *(const bf16x8*)(Vs + (d * 16 + lc) * 64 + co);
        o[0][d] = __builtin_amdgcn_mfma_f32_16x16x32_bf16(pa[0][ks], vfr, o[0][d], 0, 0, 0);
        o[1][d] = __builtin_amdgcn_mfma_f32_16x16x32_bf16(pa[1][ks], vfr, o[1][d], 0, 0, 0);
      }
    }
    __syncthreads();
  }

  // finalize + store bf16 [B][N][C]
  const int b = bh >> 4, h = bh & 15;
  #pragma unroll
  for (int f = 0; f < 2; ++f) {
    float linv = 1.0f / l_r[f];
    #pragma unroll
    for (int r = 0; r < 4; ++r) {
      float li = __shfl(linv, lg * 4 + r, 16);
      int n = qt * 128 + wid * 32 + f * 16 + lg * 4 + r;
      u16* dst = O + ((size_t)b * 1024 + n) * 1024 + h * 64 + lc;
      #pragma unroll
      for (int d = 0; d < 4; ++d) dst[d * 16] = f2bf(o[f][d][r] * li);
    }
  }
}

// ---------------------------------------------------------------------------
// Projection GEMM (m97 structure), unchanged.
// ---------------------------------------------------------------------------
__global__ __launch_bounds__(256, 2) void proj_gemm2(
    const u16* __restrict__ Ab, const u16* __restrict__ Wt,
    const float* __restrict__ bias, float* __restrict__ Out)
{
  constexpr int KD = 1024, NCOL = 1024;
  __shared__ __align__(16) u16 As[128 * 32];
  __shared__ __align__(16) u16 Bs[128 * 32];

  const int tid = threadIdx.x;
  const int lane = tid & 63, wid = tid >> 6;
  const int wr = wid >> 1, wc = wid & 1;
  const int lg = lane >> 4, lc = lane & 15;
  const int row0 = blockIdx.x * 128, col0 = blockIdx.y * 128;

  f32x4 acc[4][4];
  #pragma unroll
  for (int m = 0; m < 4; ++m)
    #pragma unroll
    for (int n = 0; n < 4; ++n) acc[m][n] = (f32x4){0.f, 0.f, 0.f, 0.f};

  const int l4 = lane >> 2, ls = (lane & 3) * 8;
  const u16* gA0 = Ab + (size_t)(row0 + wid * 16 + l4) * KD + ls;
  const u16* gB0 = Wt + (size_t)(col0 + wid * 16 + l4) * KD + ls;
  u16* lA0 = As + wid * 512;
  u16* lB0 = Bs + wid * 512;

  for (int k0 = 0; k0 < KD; k0 += 32) {
    gload16(gA0 + k0, lA0, lane);
    gload16(gA0 + 64 * KD + k0, lA0 + 2048, lane);
    gload16(gB0 + k0, lB0, lane);
    gload16(gB0 + 64 * KD + k0, lB0 + 2048, lane);
    __syncthreads();

    bf16x8 a[4], b[4];
    #pragma unroll
    for (int m = 0; m < 4; ++m)
      a[m] = *(const bf16x8*)(As + (wr * 64 + m * 16 + lc) * 32 + lg * 8);
    #pragma unroll
    for (int n = 0; n < 4; ++n)
      b[n] = *(const bf16x8*)(Bs + (wc * 64 + n * 16 + lc) * 32 + lg * 8);
    #pragma unroll
    for (int m = 0; m < 4; ++m)
      #pragma unroll
      for (int n = 0; n < 4; ++n)
        acc[m][n] = __builtin_amdgcn_mfma_f32_16x16x32_bf16(a[m], b[n], acc[m][n], 0, 0, 0);
    __syncthreads();
  }

  #pragma unroll
  for (int m = 0; m < 4; ++m) {
    #pragma unroll
    for (int n = 0; n < 4; ++n) {
      #pragma unroll
      for (int r = 0; r < 4; ++r) {
        int gr = row0 + wr * 64 + m * 16 + lg * 4 + r;
        int gc = col0 + wc * 64 + n * 16 + lc;
        Out[(size_t)gr * NCOL + gc] = acc[m][n][r] + bias[gc];
      }
    }
  }
}

// ---------------------------------------------------------------------------
extern "C" void kernel_launch(void* const* d_in, const int* in_sizes, int n_in,
                              void* d_out, int out_size, void* d_ws, size_t ws_size,
                              hipStream_t stream) {
  const float* x     = (const float*)d_in[0];
  const float* W_qkv = (const float*)d_in[1];
  const float* b_qkv = (const float*)d_in[2];
  const float* W_prj = (const float*)d_in[3];
  const float* b_prj = (const float*)d_in[4];
  float* out = (float*)d_out;

  const size_t SEG = (size_t)8192 * 1024;   // 8388608 elems (u16)
  char* ws = (char*)d_ws;
  u16* Xb  = (u16*)ws;                       // dead after qkv
  u16* Ab  = Xb;                             // alias: attn output
  u16* VtG = (u16*)(ws + SEG * 2);           // V transposed [bh][64][1024]
  u16* Wqt = (u16*)(ws + SEG * 4);
  u16* Wpt = Wqt + (size_t)3072 * 1024;
  u16* Qb  = (u16*)d_out;                    // d_out as scratch
  u16* Kb  = Qb + SEG;

  convert_f32_bf16<<<4096, 256, 0, stream>>>(x, Xb);
  transpose_w<<<dim3(48, 16), 256, 0, stream>>>(W_qkv, Wqt, 1024, 3072);
  transpose_w<<<dim3(16, 16), 256, 0, stream>>>(W_prj, Wpt, 1024, 1024);
  qkv_gemm2<<<dim3(64, 24), 256, 0, stream>>>(Xb, Wqt, b_qkv, Qb, Kb, VtG);
  attn_kernel<<<dim3(128, 8), 256, 0, stream>>>(Qb, Kb, VtG, Ab);
  proj_gemm2<<<dim3(64, 8), 256, 0, stream>>>(Ab, Wpt, b_prj, out);
}